// Round 4
// baseline (129.348 us; speedup 1.0000x reference)
//
#include <hip/hip_runtime.h>
#include <hip/hip_bf16.h>
#include <stdint.h>

using bf16   = __bf16;
using bf16x4 = __attribute__((ext_vector_type(4))) __bf16;
using bf16x8 = __attribute__((ext_vector_type(8))) __bf16;
using f32x4  = __attribute__((ext_vector_type(4))) float;

// geometry (fixed by the problem)
static constexpr int BATCH = 4, SEQ = 2048, DIM = 512, HEADS = 8, DK = 64;
static constexpr int M    = BATCH * SEQ;   // 8192 rows of x
static constexpr int NQKV = 3 * DIM;       // 1536

#define GLD16(src, dst)                                                        \
    __builtin_amdgcn_global_load_lds(                                          \
        (const __attribute__((address_space(1))) void*)(src),                  \
        (__attribute__((address_space(3))) void*)(dst), 16, 0, 0)

// ---------------------------------------------------------------------------
// Kernel 1: x -> bf16; W [512][1536] fp32 -> Wt [1536][512] bf16; zero S.
// ---------------------------------------------------------------------------
__global__ __launch_bounds__(256) void k_prep(const float* __restrict__ x,
                                              const float* __restrict__ w,
                                              bf16* __restrict__ xbf,
                                              bf16* __restrict__ wt,
                                              float* __restrict__ S)
{
    const int bid = blockIdx.x;
    const int t   = threadIdx.x;
    const int XB  = (M * DIM) / (256 * 4);                 // 4096 blocks
    const int WB  = (DIM / 32) * (NQKV / 32);              // 768 blocks

    if (bid < XB) {
        const int i = (bid * 256 + t) * 4;
        float4 v = *(const float4*)(x + i);
        bf16x4 o = { (bf16)v.x, (bf16)v.y, (bf16)v.z, (bf16)v.w };
        *(bf16x4*)(xbf + i) = o;
    } else if (bid < XB + WB) {
        const int wb = bid - XB;
        const int rt = wb / 48, ct = wb - rt * 48;          // k-tile, n-tile
        __shared__ float tile[32][33];
        const int r = t >> 5, c = t & 31;
        #pragma unroll
        for (int i = 0; i < 4; ++i)
            tile[r + i * 8][c] = w[(rt * 32 + r + i * 8) * NQKV + ct * 32 + c];
        __syncthreads();
        #pragma unroll
        for (int i = 0; i < 4; ++i)
            wt[(ct * 32 + r + i * 8) * DIM + rt * 32 + c] = (bf16)tile[c][r + i * 8];
    } else {
        const int sb = bid - XB - WB;                       // 128 blocks
        const int i  = (sb * 256 + t) * 4;
        *(f32x4*)(S + i) = (f32x4){0.f, 0.f, 0.f, 0.f};
    }
}

// ---------------------------------------------------------------------------
// Kernel 2 (mega): per (m-tile 128, head h): GEMM cols {q_h|k_h|v_h}
// (128x192, 6 waves of 64x64).  Double-buffered LDS (2-phase): next K-tile's
// 40 global_load_lds are issued BEFORE computing the current tile, so load
// latency hides under MFMA; single __syncthreads per step (drain overlapped).
// Fused epilogue: q-waves LN->transpose->qn; k-waves LN->kst LDS; v-waves
// cast->vst LDS; then v-waves MFMA the 128-row partial S and atomicAdd.
// ---------------------------------------------------------------------------
__global__ __launch_bounds__(384) void k_gemm(const bf16* __restrict__ xbf,
                                              const bf16* __restrict__ Wt,
                                              const float* __restrict__ gq,
                                              const float* __restrict__ bq,
                                              const float* __restrict__ gk,
                                              const float* __restrict__ bk,
                                              bf16* __restrict__ qn,
                                              float* __restrict__ S)
{
    __shared__ union {
        struct { bf16 A[2][128 * 64]; bf16 B[2][192 * 64]; } g;            // 80 KB
        struct { bf16 q[2][64][72]; bf16 kst[64 * 128]; bf16 vst[64 * 128]; } e; // 50 KB
    } u;

    const int t    = threadIdx.x;
    const int lane = t & 63, wave = t >> 6;      // 6 waves
    const int wm   = wave & 1, ws = wave >> 1;   // row-half, section (q/k/v)
    const int orig = blockIdx.x;                 // 512 blocks, 512 % 8 == 0
    const int wg   = (orig & 7) * 64 + (orig >> 3);  // XCD-contiguous
    const int mt   = wg >> 3, h = wg & 7;
    const int m0   = mt * 128;

    const int l15 = lane & 15, l4 = lane >> 4;
    const int rl  = lane >> 3, cl = (lane & 7) ^ rl;   // swizzled GLD src chunk

    // stage one K-tile (40 x 1KB chunks: 16 A + 24 B) into buffer `buf`
    auto stage = [&](int buf, int k0) {
        for (int c = wave; c < 40; c += 6) {
            if (c < 16) {
                const int r = c * 8 + rl;                  // tile row 0..127
                GLD16(xbf + (m0 + r) * 512 + k0 + cl * 8, u.g.A[buf] + c * 512);
            } else {
                const int ch  = c - 16;                    // 0..23
                const int sec = ch >> 3;                   // 0=q 1=k 2=v
                const int r   = (ch & 7) * 8 + rl;         // row in section
                GLD16(Wt + ((sec * 512 + h * 64 + r) * 512 + k0 + cl * 8),
                      u.g.B[buf] + ch * 512);
            }
        }
    };

    f32x4 acc[4][4] = {};

    stage(0, 0);
    __syncthreads();                 // implicit vmcnt(0) drain + barrier
    int cur = 0;
    for (int it = 0; it < 8; ++it) {
        if (it < 7) stage(cur ^ 1, (it + 1) * 64);   // issue next tile first
        #pragma unroll
        for (int kh = 0; kh < 2; ++kh) {
            bf16x8 af[4], bfv[4];
            const int rc = kh * 4 + l4;
            #pragma unroll
            for (int mf = 0; mf < 4; ++mf) {
                const int row = wm * 64 + mf * 16 + l15;
                af[mf] = *(const bf16x8*)(u.g.A[cur] + row * 64 + ((rc ^ (row & 7)) * 8));
            }
            #pragma unroll
            for (int nf = 0; nf < 4; ++nf) {
                const int row = ws * 64 + nf * 16 + l15;   // 0..191
                bfv[nf] = *(const bf16x8*)(u.g.B[cur] + row * 64 + ((rc ^ (row & 7)) * 8));
            }
            #pragma unroll
            for (int mf = 0; mf < 4; ++mf)
                #pragma unroll
                for (int nf = 0; nf < 4; ++nf)
                    acc[mf][nf] = __builtin_amdgcn_mfma_f32_16x16x32_bf16(
                        af[mf], bfv[nf], acc[mf][nf], 0, 0, 0);
        }
        __syncthreads();             // next-tile loads landed; cur free to reuse
        cur ^= 1;
    }

    // ---------------- fused epilogue (aliases g; barrier above protects) ----
    const int b  = m0 >> 11;
    const int bh = b * 8 + h;
    const int nwbase = (m0 & 2047) + wm * 64;    // seq offset of wave's 64 rows

    if (ws < 2) {
        // LayerNorm over d=64 (4 nf frags x 16 l15 lanes), stats from fp32 acc
        const float* gp = (ws == 0 ? gq : gk) + h * 64;
        const float* bp = (ws == 0 ? bq : bk) + h * 64;
        float gv[4], bv[4];
        #pragma unroll
        for (int nf = 0; nf < 4; ++nf) {
            gv[nf] = gp[nf * 16 + l15];
            bv[nf] = bp[nf * 16 + l15];
        }
        #pragma unroll
        for (int mf = 0; mf < 4; ++mf) {
            float mu[4], rs[4];
            #pragma unroll
            for (int r = 0; r < 4; ++r) {
                float s = 0.f, s2 = 0.f;
                #pragma unroll
                for (int nf = 0; nf < 4; ++nf) {
                    const float xv = acc[mf][nf][r];
                    s += xv; s2 += xv * xv;
                }
                s  += __shfl_xor(s, 1);  s  += __shfl_xor(s, 2);
                s  += __shfl_xor(s, 4);  s  += __shfl_xor(s, 8);
                s2 += __shfl_xor(s2, 1); s2 += __shfl_xor(s2, 2);
                s2 += __shfl_xor(s2, 4); s2 += __shfl_xor(s2, 8);
                mu[r] = s * (1.f / 64.f);
                rs[r] = rsqrtf(s2 * (1.f / 64.f) - mu[r] * mu[r] + 1e-5f);
            }
            #pragma unroll
            for (int nf = 0; nf < 4; ++nf) {
                bf16x4 pk;
                #pragma unroll
                for (int r = 0; r < 4; ++r)
                    pk[r] = (bf16)((acc[mf][nf][r] - mu[r]) * rs[r] * gv[nf] + bv[nf]);
                if (ws == 0) {
                    *(bf16x4*)(&u.e.q[wm][nf * 16 + l15][mf * 16 + l4 * 4]) = pk;
                } else {
                    const int d = nf * 16 + l15;
                    const int c = wm * 8 + mf * 2 + (l4 >> 1);   // n-chunk 0..15
                    *(bf16x4*)(u.e.kst + d * 128 + ((c ^ (d & 7)) * 8) + (l4 & 1) * 4) = pk;
                }
            }
        }
    } else {
        // v: plain cast into vst[d'][128n], same swizzle
        #pragma unroll
        for (int mf = 0; mf < 4; ++mf)
            #pragma unroll
            for (int nf = 0; nf < 4; ++nf) {
                bf16x4 pk;
                #pragma unroll
                for (int r = 0; r < 4; ++r) pk[r] = (bf16)acc[mf][nf][r];
                const int d = nf * 16 + l15;
                const int c = wm * 8 + mf * 2 + (l4 >> 1);
                *(bf16x4*)(u.e.vst + d * 128 + ((c ^ (d & 7)) * 8) + (l4 & 1) * 4) = pk;
            }
    }

    if (ws == 0) {
        // wave-local 4x4 transpose qep[d][n] -> qn[bh][n][d]
        bf16* dst = qn + ((long)bh * SEQ + nwbase) * 64;
        const int nq = lane & 15, dq2 = lane >> 4;
        #pragma unroll
        for (int j = 0; j < 4; ++j) {
            const int d0 = (j * 4 + dq2) * 4;
            bf16x4 a0 = *(const bf16x4*)(&u.e.q[wm][d0 + 0][nq * 4]);
            bf16x4 a1 = *(const bf16x4*)(&u.e.q[wm][d0 + 1][nq * 4]);
            bf16x4 a2 = *(const bf16x4*)(&u.e.q[wm][d0 + 2][nq * 4]);
            bf16x4 a3 = *(const bf16x4*)(&u.e.q[wm][d0 + 3][nq * 4]);
            #pragma unroll
            for (int c = 0; c < 4; ++c) {
                bf16x4 o = { a0[c], a1[c], a2[c], a3[c] };
                *(bf16x4*)(dst + (nq * 4 + c) * 64 + d0) = o;
            }
        }
    }

    __syncthreads();   // kst/vst complete for all waves

    if (ws == 2) {
        // partial S[d'][d] over this block's 128 rows; wave wm does ks pair
        f32x4 sac[4][4] = {};
        #pragma unroll
        for (int kk = 0; kk < 2; ++kk) {
            const int ksi = wm * 2 + kk;          // 0..3 (n-chunk of 32)
            const int c   = ksi * 4 + l4;         // 16B chunk 0..15
            bf16x8 av[4], bk8[4];
            #pragma unroll
            for (int i = 0; i < 4; ++i) {
                const int dp = i * 16 + l15;
                av[i] = *(const bf16x8*)(u.e.vst + dp * 128 + ((c ^ (dp & 7)) * 8));
            }
            #pragma unroll
            for (int j = 0; j < 4; ++j) {
                const int dd = j * 16 + l15;
                bk8[j] = *(const bf16x8*)(u.e.kst + dd * 128 + ((c ^ (dd & 7)) * 8));
            }
            #pragma unroll
            for (int i = 0; i < 4; ++i)
                #pragma unroll
                for (int j = 0; j < 4; ++j)
                    sac[i][j] = __builtin_amdgcn_mfma_f32_16x16x32_bf16(
                        av[i], bk8[j], sac[i][j], 0, 0, 0);
        }
        float* Sb = S + bh * 4096;
        #pragma unroll
        for (int i = 0; i < 4; ++i)
            #pragma unroll
            for (int j = 0; j < 4; ++j)
                #pragma unroll
                for (int r = 0; r < 4; ++r) {
                    const int dp = i * 16 + l4 * 4 + r;   // d'
                    const int dd = j * 16 + l15;          // d
                    atomicAdd(Sb + dp * 64 + dd, sac[i][j][r]);
                }
    }
}

// ---------------------------------------------------------------------------
// Kernel 3: out[b][n][h*64+d'] = sum_d qn[bh][n][d] * (S[bh][d'][d] * 2^-14)
// 512 blocks x 4 waves; each wave owns 32 seq rows (2048 waves -> 8/CU).
// Scale folded into the S->bf16 conversion (exact power of two).
// ---------------------------------------------------------------------------
__global__ __launch_bounds__(256) void k_out(const bf16* __restrict__ qn,
                                             const float* __restrict__ S,
                                             float* __restrict__ out)
{
    const int bid = blockIdx.x;
    const int bh = bid >> 4, nt4 = bid & 15;
    const int b = bh >> 3, h = bh & 7;
    const int t = threadIdx.x, lane = t & 63, wave = t >> 6;
    const int l15 = lane & 15, l4 = lane >> 4;
    const float* Sb = S + bh * 4096;
    const float scale = 1.f / 16384.f;   // (64^-0.5)/2048 exactly

    bf16x8 bfr[2][4];
    #pragma unroll
    for (int kh = 0; kh < 2; ++kh)
        #pragma unroll
        for (int cf = 0; cf < 4; ++cf) {
            const float* p = Sb + (cf * 16 + l15) * 64 + kh * 32 + l4 * 8;
            float4 lo = *(const float4*)(p);
            float4 hi = *(const float4*)(p + 4);
            bf16x8 f;
            f[0] = (bf16)(lo.x * scale); f[1] = (bf16)(lo.y * scale);
            f[2] = (bf16)(lo.z * scale); f[3] = (bf16)(lo.w * scale);
            f[4] = (bf16)(hi.x * scale); f[5] = (bf16)(hi.y * scale);
            f[6] = (bf16)(hi.z * scale); f[7] = (bf16)(hi.w * scale);
            bfr[kh][cf] = f;
        }

    const bf16* qb = qn + (long)bh * SEQ * 64;
    const int nbase = nt4 * 128 + wave * 32;

    #pragma unroll
    for (int mf = 0; mf < 2; ++mf) {
        bf16x8 a0 = *(const bf16x8*)(qb + (nbase + mf * 16 + l15) * 64 +      l4 * 8);
        bf16x8 a1 = *(const bf16x8*)(qb + (nbase + mf * 16 + l15) * 64 + 32 + l4 * 8);
        f32x4 acc[4] = {};
        #pragma unroll
        for (int cf = 0; cf < 4; ++cf) {
            acc[cf] = __builtin_amdgcn_mfma_f32_16x16x32_bf16(a0, bfr[0][cf], acc[cf], 0, 0, 0);
            acc[cf] = __builtin_amdgcn_mfma_f32_16x16x32_bf16(a1, bfr[1][cf], acc[cf], 0, 0, 0);
        }
        #pragma unroll
        for (int cf = 0; cf < 4; ++cf)
            #pragma unroll
            for (int r = 0; r < 4; ++r) {
                const int n = nbase + mf * 16 + l4 * 4 + r;
                out[((long)b * SEQ + n) * 512 + h * 64 + cf * 16 + l15] = acc[cf][r];
            }
    }
}

// ---------------------------------------------------------------------------
extern "C" void kernel_launch(void* const* d_in, const int* in_sizes, int n_in,
                              void* d_out, int out_size, void* d_ws, size_t ws_size,
                              hipStream_t stream)
{
    const float* x  = (const float*)d_in[0];
    const float* w  = (const float*)d_in[1];
    const float* gq = (const float*)d_in[2];
    const float* bq = (const float*)d_in[3];
    const float* gk = (const float*)d_in[4];
    const float* bk = (const float*)d_in[5];
    float* out = (float*)d_out;

    char* ws = (char*)d_ws;
    // layout (bytes):
    //   xbf bf16 : 0        .. 8388608
    //   wt  bf16 : 8388608  .. 9961472
    //   qn  bf16 : 9961472  .. 18350080
    //   S   fp32 : 18350080 .. 18874368   (~18 MB total)
    bf16*  xbf = (bf16*)(ws);
    bf16*  wt  = (bf16*)(ws + 8388608);
    bf16*  qn  = (bf16*)(ws + 9961472);
    float* S   = (float*)(ws + 18350080);

    hipLaunchKernelGGL(k_prep, dim3(4096 + 768 + 128), dim3(256), 0, stream,
                       x, w, xbf, wt, S);
    hipLaunchKernelGGL(k_gemm, dim3(512), dim3(384), 0, stream,
                       xbf, wt, gq, bq, gk, bk, qn, S);
    hipLaunchKernelGGL(k_out,  dim3(512), dim3(256), 0, stream, qn, S, out);
}